// Round 9
// baseline (6557.833 us; speedup 1.0000x reference)
//
#include <hip/hip_runtime.h>

#define BB 128
#define TT 1024
#define INP 54
#define HUM 64
#define NPSI 96540
#define OFF_BH 65536
#define OFF_WIH 65792
#define OFF_C 79616
#define OFF_D 96000
#define OUT_MU 8388608
#define OUT_LS 8390656
#define OUT_HL 8392704

typedef unsigned int u32;
typedef unsigned short u16;
typedef _Float16 h2 __attribute__((ext_vector_type(2)));

__device__ __forceinline__ u32 pk(float a, float b) {
    h2 v; v.x = (_Float16)a; v.y = (_Float16)b;
    return __builtin_bit_cast(u32, v);
}
__device__ __forceinline__ float f16tof(u16 v) {
    return (float)__builtin_bit_cast(_Float16, v);
}
__device__ __forceinline__ u16 ftof16(float v) {
    return __builtin_bit_cast(u16, (_Float16)v);
}
__device__ __forceinline__ float lo16f(u32 v) { return f16tof((u16)(v & 0xffffu)); }
__device__ __forceinline__ float hi16f(u32 v) { return f16tof((u16)(v >> 16)); }
__device__ __forceinline__ h2 bch2(u32 a) { return __builtin_bit_cast(h2, a); }
// v_dot2_f32_f16: 2 f16 MACs + f32 accumulate
__device__ __forceinline__ float fd2(u32 a, u32 b, float c) {
#if __has_builtin(__builtin_amdgcn_fdot2)
    return __builtin_amdgcn_fdot2(bch2(a), bch2(b), c, false);
#else
    return c + lo16f(a) * lo16f(b) + hi16f(a) * hi16f(b);
#endif
}
__device__ __forceinline__ float fsig(float x) { return 1.f / (1.f + __expf(-x)); }
__device__ __forceinline__ float ftanh(float x) { float e = __expf(2.f * x); return 1.f - 2.f / (e + 1.f); }

// ------------------------------------------------------- x-side projections --
__global__ __launch_bounds__(768, 3) void gemm_x_kernel(
    const float* __restrict__ inp, const float* __restrict__ W0,
    const u16* __restrict__ psi16, int mode, int t0, int len, int ct, int nt,
    u16* __restrict__ gout)
{
    const int tid = threadIdx.x;
    const int b = blockIdx.x / nt, tc = blockIdx.x % nt;
    const int gr = tid;
    float w[INP];
    if (mode == 0 || gr < 512) {
        const float* wsrc = W0 + (size_t)gr * INP;
#pragma unroll
        for (int c = 0; c < INP; ++c) w[c] = wsrc[c];
    } else {
        const u16* wsrc = psi16 + (size_t)b * NPSI + OFF_WIH + (size_t)(gr - 512) * INP;
#pragma unroll
        for (int c = 0; c < INP; ++c) w[c] = f16tof(wsrc[c]);
    }
    const int tb = tc * 128;
    const int te = (tb + 128 < len) ? tb + 128 : len;
    for (int tl = tb; tl < te; ++tl) {
        const float* xr = inp + ((size_t)b * TT + t0 + tl) * INP;
        float a = 0.f;
#pragma unroll
        for (int c = 0; c < INP; ++c) a = __builtin_fmaf(xr[c], w[c], a);
        gout[((size_t)b * ct + tl) * 768 + gr] = ftof16(a);
    }
}

// ---------------------------------------------------------------- encoder ---
// 256 thr, 1 wave/SIMD (waves_per_eu(1,1) -> 512-reg budget). Thread j owns
// rows r=j, z=256+j, n=512+j with FULL K in-thread: 384 weight-u32, no
// cross-lane reduce. h exchange: LDS broadcast, conflict-free.
__global__ __launch_bounds__(256) __attribute__((amdgpu_waves_per_eu(1, 1)))
void enc_scan_kernel(
    const u16* __restrict__ gi, int t0, int len, int ct,
    const float* __restrict__ Whh, const float* __restrict__ bih,
    const float* __restrict__ bhh, float* __restrict__ hcarry)
{
    __shared__ __align__(16) u32 hpp[2][128];
    const int tid = threadIdx.x, b = blockIdx.x;
    const int j = tid;

    u32 wr[128], wz[128], wn[128];
    {
        const float* pr = Whh + (size_t)j * 256;
        const float* pz = Whh + (size_t)(256 + j) * 256;
        const float* pn = Whh + (size_t)(512 + j) * 256;
#pragma unroll
        for (int c = 0; c < 128; ++c) {
            wr[c] = pk(pr[2 * c], pr[2 * c + 1]);
            wz[c] = pk(pz[2 * c], pz[2 * c + 1]);
            wn[c] = pk(pn[2 * c], pn[2 * c + 1]);
        }
    }
    const float brb = bih[j] + bhh[j];
    const float bzb = bih[256 + j] + bhh[256 + j];
    const float bib = bih[512 + j];
    const float bhb = bhh[512 + j];
    float hc = 0.f;
    if (t0 > 0) hc = hcarry[(size_t)b * 256 + j];
    if (tid < 128) {
        u32 hv = 0u;
        if (t0 > 0) hv = pk(hcarry[(size_t)b * 256 + 2 * tid], hcarry[(size_t)b * 256 + 2 * tid + 1]);
        hpp[0][tid] = hv;
    }
    __syncthreads();

    const u16* gbase = gi + (size_t)b * ct * 768;
    u16 c0 = gbase[j], c1 = gbase[256 + j], c2 = gbase[512 + j];

    for (int tl = 0; tl < len; ++tl) {
        const int p = tl & 1;
        u16 n0 = 0, n1 = 0, n2 = 0;
        if (tl + 1 < len) {
            const u16* gn = gbase + (size_t)(tl + 1) * 768;
            n0 = gn[j]; n1 = gn[256 + j]; n2 = gn[512 + j];
        }
        float ar[4] = {0, 0, 0, 0}, az[4] = {0, 0, 0, 0}, an[4] = {0, 0, 0, 0};
        const uint4* hq = (const uint4*)hpp[p];
#pragma unroll
        for (int cc = 0; cc < 32; ++cc) {
            uint4 q = hq[cc];
            u32 qa[4] = {q.x, q.y, q.z, q.w};
#pragma unroll
            for (int u = 0; u < 4; ++u) {
                const int c = 4 * cc + u;
                ar[u] = fd2(wr[c], qa[u], ar[u]);
                az[u] = fd2(wz[c], qa[u], az[u]);
                an[u] = fd2(wn[c], qa[u], an[u]);
            }
        }
        const float Ar = (ar[0] + ar[1]) + (ar[2] + ar[3]);
        const float Az = (az[0] + az[1]) + (az[2] + az[3]);
        const float An = (an[0] + an[1]) + (an[2] + an[3]);
        {
            float r = fsig(Ar + f16tof(c0) + brb);
            float z = fsig(Az + f16tof(c1) + bzb);
            float nn = ftanh(f16tof(c2) + bib + r * (An + bhb));
            float hn = (1.f - z) * nn + z * hc;
            hc = hn;
            float ho = __shfl_xor(hn, 1);
            if (!(tid & 1)) hpp[p ^ 1][tid >> 1] = pk(hn, ho);
        }
        c0 = n0; c1 = n1; c2 = n2;
        __syncthreads();
    }
    hcarry[(size_t)b * 256 + j] = hc;
}

// ----------------------------------------------------------------- latent ---
__global__ __launch_bounds__(256) void latent_kernel(
    const float* __restrict__ henc, const float* __restrict__ eps,
    const float* __restrict__ to_mu, const float* __restrict__ to_ls,
    const float* __restrict__ W1, const float* __restrict__ b1,
    const float* __restrict__ W2, const float* __restrict__ b2,
    float* __restrict__ psi2, float* __restrict__ out)
{
    __shared__ float h[256], zz[16], p1[256];
    const int tid = threadIdx.x, b = blockIdx.x;
    h[tid] = henc[(size_t)b * 256 + tid];
    __syncthreads();
    if (tid < 16) {
        float m = 0, s = 0;
        for (int k = 0; k < 256; ++k) {
            m += h[k] * to_mu[tid * 256 + k];
            s += h[k] * to_ls[tid * 256 + k];
        }
        out[OUT_MU + b * 16 + tid] = m;
        out[OUT_LS + b * 16 + tid] = s;
        zz[tid] = m + eps[b * 16 + tid] * __expf(s);
    }
    __syncthreads();
    {
        float a = b1[tid];
        for (int k = 0; k < 16; ++k) a += zz[k] * W1[tid * 16 + k];
        p1[tid] = ftanh(a);
    }
    __syncthreads();
    if (tid < 32) {
        float a = b2[tid];
        for (int k = 0; k < 256; ++k) a += p1[k] * W2[tid * 256 + k];
        psi2[b * 32 + tid] = a;
    }
}

// ------------------------------------------------------------------- psi3 ---
__global__ __launch_bounds__(256) void psi3_kernel(
    const float* __restrict__ psi2, const float* __restrict__ W3,
    const float* __restrict__ b3, u16* __restrict__ psi16)
{
    __shared__ float sp2[128 * 32];
    __shared__ float w3t[256 * 33];
    const int tid = threadIdx.x;
    const int n0 = blockIdx.x * 256;
    for (int idx = tid; idx < 4096; idx += 256) sp2[idx] = psi2[idx];
    for (int idx = tid; idx < 8192; idx += 256) {
        int row = idx >> 5, k = idx & 31;
        int n = n0 + row;
        w3t[row * 33 + k] = (n < NPSI) ? W3[(size_t)n * 32 + k] : 0.f;
    }
    __syncthreads();
    const int n = n0 + tid;
    if (n < NPSI) {
        float w[32];
#pragma unroll
        for (int k = 0; k < 32; ++k) w[k] = w3t[tid * 33 + k];
        const float bv = b3[n];
        for (int bi = 0; bi < 128; ++bi) {
            float a = bv;
#pragma unroll
            for (int k = 0; k < 32; ++k) a += sp2[bi * 32 + k] * w[k];
            psi16[(size_t)bi * NPSI + n] = ftof16(a);
        }
    }
}

// ------------------------------- decoder scan + pipelined fused C_p einsum --
// 256 thr, 1 wave/SIMD. Thread j owns z-col j, r-col 256+j (gWhh) and p-row j
// (Whh_p) with full K in-thread. yhat: o=tid&63, s=tid>>6 (4 slices of 32).
__global__ __launch_bounds__(256) __attribute__((amdgpu_waves_per_eu(1, 1)))
void dec_scan_kernel(
    const u16* __restrict__ gx, int t0, int len, int ct,
    const float* __restrict__ state, const float* __restrict__ gWhh,
    const float* __restrict__ gbias, const u16* __restrict__ psi16,
    float* __restrict__ dcarry, float* __restrict__ out)
{
    __shared__ __align__(16) u32 hpp[2][128];
    __shared__ u32 cp[64 * 129];      // [o][pair q], stride 129 -> 2-way free
    __shared__ float part[2][4 * 64];
    const int tid = threadIdx.x, b = blockIdx.x;
    const int j = tid;
    const u16* pc = psi16 + (size_t)b * NPSI;

    u32 wz[128], wrr[128], wp[128];
    {
        const float* srcz = gWhh + j;
        const float* srcr = gWhh + 256 + j;
        const u16* srcp = pc + j;
#pragma unroll
        for (int c = 0; c < 128; ++c) {
            wz[c]  = pk(srcz[(size_t)(2 * c) * 512], srcz[(size_t)(2 * c + 1) * 512]);
            wrr[c] = pk(srcr[(size_t)(2 * c) * 512], srcr[(size_t)(2 * c + 1) * 512]);
            wp[c]  = (u32)srcp[(size_t)(2 * c) * 256] | ((u32)srcp[(size_t)(2 * c + 1) * 256] << 16);
        }
    }
    const float gzb = gbias[j];
    const float grb = gbias[256 + j];
    const float bhb = f16tof(pc[OFF_BH + j]);
    for (int idx = tid; idx < 8192; idx += 256) {
        const int q = idx >> 6, o = idx & 63;
        cp[o * 129 + q] = (u32)pc[OFF_C + (size_t)(2 * q) * 64 + o]
                        | ((u32)pc[OFF_C + (size_t)(2 * q + 1) * 64 + o] << 16);
    }
    const float* hsrc = (t0 == 0) ? state : dcarry;
    float hc = hsrc[(size_t)b * 256 + j];
    if (tid < 128) hpp[0][tid] =
        pk(hsrc[(size_t)b * 256 + 2 * tid], hsrc[(size_t)b * 256 + 2 * tid + 1]);
    __syncthreads();

    const u16* gbase = gx + (size_t)b * ct * 768;
    const int o = tid & 63, s = tid >> 6;       // s = wave id (uniform)
    u16 c0 = gbase[j], c1 = gbase[256 + j], c2 = gbase[512 + j];

    for (int tl = 0; tl < len; ++tl) {
        const int p = tl & 1;
        u16 n0 = 0, n1 = 0, n2 = 0;
        if (tl + 1 < len) {
            const u16* gn = gbase + (size_t)(tl + 1) * 768;
            n0 = gn[j]; n1 = gn[256 + j]; n2 = gn[512 + j];
        }
        // yhat partials for h_{t0+tl-1}: slice s covers pairs [32s, 32s+32)
        {
            const uint4* h2q = (const uint4*)&hpp[p][32 * s];
            const int cbase = o * 129 + 32 * s;
            float p0 = 0.f, p1 = 0.f;
#pragma unroll
            for (int i = 0; i < 8; ++i) {
                uint4 q = h2q[i];
                p0 = fd2(q.x, cp[cbase + 4 * i + 0], p0);
                p1 = fd2(q.y, cp[cbase + 4 * i + 1], p1);
                p0 = fd2(q.z, cp[cbase + 4 * i + 2], p0);
                p1 = fd2(q.w, cp[cbase + 4 * i + 3], p1);
            }
            part[p][s * 64 + o] = p0 + p1;
        }
        // reduce partials of h_{t0+tl-2} -> y_{t0+tl-2}
        if (tid < 64 && tl >= 2) {
            float y = (part[p ^ 1][tid] + part[p ^ 1][64 + tid])
                    + (part[p ^ 1][128 + tid] + part[p ^ 1][192 + tid]);
            out[((size_t)b * TT + t0 + tl - 2) * HUM + tid] = y;
        }
        // recurrent matvec: full K in-thread, 12 independent chains
        float az[4] = {0, 0, 0, 0}, ar[4] = {0, 0, 0, 0}, ap[4] = {0, 0, 0, 0};
        const uint4* hq = (const uint4*)hpp[p];
#pragma unroll
        for (int cc = 0; cc < 32; ++cc) {
            uint4 q = hq[cc];
            u32 qa[4] = {q.x, q.y, q.z, q.w};
#pragma unroll
            for (int u = 0; u < 4; ++u) {
                const int c = 4 * cc + u;
                az[u] = fd2(wz[c], qa[u], az[u]);
                ar[u] = fd2(wrr[c], qa[u], ar[u]);
                ap[u] = fd2(wp[c], qa[u], ap[u]);
            }
        }
        const float Az = (az[0] + az[1]) + (az[2] + az[3]);
        const float Ar = (ar[0] + ar[1]) + (ar[2] + ar[3]);
        const float Ap = (ap[0] + ap[1]) + (ap[2] + ap[3]);
        {
            float zt = fsig(Az + f16tof(c0) + gzb);
            float rt = fsig(Ar + f16tof(c1) + grb);
            float eta = ftanh(f16tof(c2) + rt * ftanh(Ap + bhb));
            float hn = zt * hc + (1.f - zt) * eta;
            hc = hn;
            float ho = __shfl_xor(hn, 1);
            if (!(tid & 1)) hpp[p ^ 1][tid >> 1] = pk(hn, ho);
        }
        c0 = n0; c1 = n1; c2 = n2;
        __syncthreads();
    }
    // tail: y_{t0+len-2} then partials+reduce for y_{t0+len-1}
    {
        const int pf = (len - 1) & 1;
        if (tid < 64 && len >= 2) {
            float y = (part[pf][tid] + part[pf][64 + tid])
                    + (part[pf][128 + tid] + part[pf][192 + tid]);
            out[((size_t)b * TT + t0 + len - 2) * HUM + tid] = y;
        }
        const int pl = len & 1;
        {
            const uint4* h2q = (const uint4*)&hpp[pl][32 * s];
            const int cbase = o * 129 + 32 * s;
            float p0 = 0.f, p1 = 0.f;
#pragma unroll
            for (int i = 0; i < 8; ++i) {
                uint4 q = h2q[i];
                p0 = fd2(q.x, cp[cbase + 4 * i + 0], p0);
                p1 = fd2(q.y, cp[cbase + 4 * i + 1], p1);
                p0 = fd2(q.z, cp[cbase + 4 * i + 2], p0);
                p1 = fd2(q.w, cp[cbase + 4 * i + 3], p1);
            }
            part[pl][s * 64 + o] = p0 + p1;
        }
        __syncthreads();
        if (tid < 64) {
            float y = (part[pl][tid] + part[pl][64 + tid])
                    + (part[pl][128 + tid] + part[pl][192 + tid]);
            out[((size_t)b * TT + t0 + len - 1) * HUM + tid] = y;
        }
    }
    dcarry[(size_t)b * 256 + j] = hc;
    if (t0 + len == TT) out[OUT_HL + (size_t)b * 256 + j] = hc;
}

// ------------------------------------------------- x add + D_p einsum fixup --
__global__ __launch_bounds__(256) void post_kernel(
    const float* __restrict__ inp, const u16* __restrict__ psi16,
    float* __restrict__ out)
{
    __shared__ float xs[128][55];
    __shared__ float ds[INP][10];
    const int tid = threadIdx.x;
    const int b = blockIdx.x >> 3, tile = blockIdx.x & 7;
    const int t0 = tile * 128;
    const u16* pc = psi16 + (size_t)b * NPSI;
    for (int idx = tid; idx < 540; idx += 256)
        ds[idx / 10][idx % 10] = f16tof(pc[OFF_D + idx]);
    for (int idx = tid; idx < 128 * INP; idx += 256) {
        const int t = idx / INP, d = idx % INP;
        xs[t][d] = inp[((size_t)b * TT + t0 + t) * INP + d];
    }
    __syncthreads();
    for (int i = 0; i < 32; ++i) {
        const int flat = i * 256 + tid;
        const int t = flat >> 6, o = flat & 63;
        const size_t oi = ((size_t)b * TT + t0 + t) * HUM + o;
        float y = out[oi];
        if (o < INP) y += xs[t][o];
        else {
            float acc = 0.f;
            for (int d = 0; d < INP; ++d) acc += xs[t][d] * ds[d][o - INP];
            y += acc;
        }
        out[oi] = y;
    }
}

// ----------------------------------------------------------------- launch ---
extern "C" void kernel_launch(void* const* d_in, const int* in_sizes, int n_in,
                              void* d_out, int out_size, void* d_ws, size_t ws_size,
                              hipStream_t stream)
{
    const float* inputs = (const float*)d_in[0];
    const float* state  = (const float*)d_in[1];
    const float* eps    = (const float*)d_in[2];
    const float* eWih   = (const float*)d_in[3];
    const float* eWhh   = (const float*)d_in[4];
    const float* ebih   = (const float*)d_in[5];
    const float* ebhh   = (const float*)d_in[6];
    const float* to_mu  = (const float*)d_in[7];
    const float* to_ls  = (const float*)d_in[8];
    const float* W1     = (const float*)d_in[9];
    const float* b1     = (const float*)d_in[10];
    const float* W2     = (const float*)d_in[11];
    const float* b2     = (const float*)d_in[12];
    const float* W3     = (const float*)d_in[13];
    const float* b3     = (const float*)d_in[14];
    const float* gWih   = (const float*)d_in[15];
    const float* gWhh   = (const float*)d_in[16];
    const float* gbias  = (const float*)d_in[17];
    float* out = (float*)d_out;
    float* ws  = (float*)d_ws;

    float* henc   = ws;
    float* psi2   = ws + 32768;
    float* dcarry = ws + 36864;
    u16*   psi16  = (u16*)(ws + 69632);
    u16*   gbuf   = (u16*)(ws + 6248192);
    const size_t used = (size_t)6248192 * 4;
    size_t avail = (ws_size > used + 4096) ? (ws_size - used - 4096) : 0;
    int ct = (int)(avail / ((size_t)BB * 768 * 2));
    if (ct > TT) ct = TT;
    if (ct < 1) ct = 1;

    for (int t0 = 0; t0 < TT; t0 += ct) {
        const int len = (TT - t0 < ct) ? (TT - t0) : ct;
        const int nt = (len + 127) / 128;
        gemm_x_kernel<<<BB * nt, 768, 0, stream>>>(inputs, eWih, psi16, 0, t0, len, ct, nt, gbuf);
        enc_scan_kernel<<<BB, 256, 0, stream>>>(gbuf, t0, len, ct, eWhh, ebih, ebhh, henc);
    }
    latent_kernel<<<BB, 256, 0, stream>>>(henc, eps, to_mu, to_ls, W1, b1, W2, b2, psi2, out);
    psi3_kernel<<<(NPSI + 255) / 256, 256, 0, stream>>>(psi2, W3, b3, psi16);
    for (int t0 = 0; t0 < TT; t0 += ct) {
        const int len = (TT - t0 < ct) ? (TT - t0) : ct;
        const int nt = (len + 127) / 128;
        gemm_x_kernel<<<BB * nt, 768, 0, stream>>>(inputs, gWih, psi16, 1, t0, len, ct, nt, gbuf);
        dec_scan_kernel<<<BB, 256, 0, stream>>>(gbuf, t0, len, ct, state, gWhh, gbias, psi16, dcarry, out);
    }
    post_kernel<<<BB * 8, 256, 0, stream>>>(inputs, psi16, out);
}